// Round 10
// baseline (623.892 us; speedup 1.0000x reference)
//
#include <hip/hip_runtime.h>
#include <math.h>

#define NH 128          // hidden size
#define NI 6            // input size
#define SIGMA_REC 0.15f
#define NCHUNK 8        // single-batch scan chunks (R17-proven)
#define NCHUNK2 16      // dual-batch scan chunks: (B/2)*16 = 1024 waves =
                        // 4/CU = 1/SIMD (same occupancy), path 759 -> 572
#define WARM 384        // warmup steps (R16/R17: absmax at 384 == f16 floor)

typedef __fp16 h2v __attribute__((ext_vector_type(2)));
typedef unsigned int vu4 __attribute__((ext_vector_type(4)));

__device__ __forceinline__ unsigned int pkh(float a, float b) {
    h2v h = __builtin_amdgcn_cvt_pkrtz(a, b);   // pack 2 f32 -> 2 f16 (RTZ)
    return __builtin_bit_cast(unsigned int, h);
}
#define H2(u) __builtin_bit_cast(h2v, (unsigned int)(u))

struct U6 { float2 a, b, c; };

// ---- load+pack one row's k-half of W: row n0+r, k in [64h, 64h+64) ----
#define LDWH(r) vu4 w##r##_0, w##r##_1, w##r##_2, w##r##_3, \
                    w##r##_4, w##r##_5, w##r##_6, w##r##_7; { \
    const float4* qp = reinterpret_cast<const float4*>( \
        W_rec + (size_t)(n0 + (r)) * NH + 64 * h); \
    float4 f0 = qp[0],  f1 = qp[1],  f2 = qp[2],  f3 = qp[3]; \
    float4 f4 = qp[4],  f5 = qp[5],  f6 = qp[6],  f7 = qp[7]; \
    float4 f8 = qp[8],  f9 = qp[9],  fA = qp[10], fB = qp[11]; \
    float4 fC = qp[12], fD = qp[13], fE = qp[14], fF = qp[15]; \
    w##r##_0 = (vu4){pkh(f0.x,f0.y), pkh(f0.z,f0.w), pkh(f1.x,f1.y), pkh(f1.z,f1.w)}; \
    w##r##_1 = (vu4){pkh(f2.x,f2.y), pkh(f2.z,f2.w), pkh(f3.x,f3.y), pkh(f3.z,f3.w)}; \
    w##r##_2 = (vu4){pkh(f4.x,f4.y), pkh(f4.z,f4.w), pkh(f5.x,f5.y), pkh(f5.z,f5.w)}; \
    w##r##_3 = (vu4){pkh(f6.x,f6.y), pkh(f6.z,f6.w), pkh(f7.x,f7.y), pkh(f7.z,f7.w)}; \
    w##r##_4 = (vu4){pkh(f8.x,f8.y), pkh(f8.z,f8.w), pkh(f9.x,f9.y), pkh(f9.z,f9.w)}; \
    w##r##_5 = (vu4){pkh(fA.x,fA.y), pkh(fA.z,fA.w), pkh(fB.x,fB.y), pkh(fB.z,fB.w)}; \
    w##r##_6 = (vu4){pkh(fC.x,fC.y), pkh(fC.z,fC.w), pkh(fD.x,fD.y), pkh(fD.z,fD.w)}; \
    w##r##_7 = (vu4){pkh(fE.x,fE.y), pkh(fE.z,fE.w), pkh(fF.x,fF.y), pkh(fF.z,fF.w)}; }

// ---- 32 pk_fma (2 chains of 16): row r's partial dot over this k-half ----
// x-source parameterized via prefix P (A or B); regs named x<P>_0..x<P>_7
// (underscore keeps the paste away from the pp-number '0.x' token).
#define ROWDOTP(r, P) h2v acc##P##r; { \
    h2v t0 = __builtin_elementwise_fma(H2(w##r##_0.x), H2(x##P##_0.x), z2); \
    h2v t1 = __builtin_elementwise_fma(H2(w##r##_0.y), H2(x##P##_0.y), z2); \
    t0 = __builtin_elementwise_fma(H2(w##r##_0.z), H2(x##P##_0.z), t0); \
    t1 = __builtin_elementwise_fma(H2(w##r##_0.w), H2(x##P##_0.w), t1); \
    t0 = __builtin_elementwise_fma(H2(w##r##_1.x), H2(x##P##_1.x), t0); \
    t1 = __builtin_elementwise_fma(H2(w##r##_1.y), H2(x##P##_1.y), t1); \
    t0 = __builtin_elementwise_fma(H2(w##r##_1.z), H2(x##P##_1.z), t0); \
    t1 = __builtin_elementwise_fma(H2(w##r##_1.w), H2(x##P##_1.w), t1); \
    t0 = __builtin_elementwise_fma(H2(w##r##_2.x), H2(x##P##_2.x), t0); \
    t1 = __builtin_elementwise_fma(H2(w##r##_2.y), H2(x##P##_2.y), t1); \
    t0 = __builtin_elementwise_fma(H2(w##r##_2.z), H2(x##P##_2.z), t0); \
    t1 = __builtin_elementwise_fma(H2(w##r##_2.w), H2(x##P##_2.w), t1); \
    t0 = __builtin_elementwise_fma(H2(w##r##_3.x), H2(x##P##_3.x), t0); \
    t1 = __builtin_elementwise_fma(H2(w##r##_3.y), H2(x##P##_3.y), t1); \
    t0 = __builtin_elementwise_fma(H2(w##r##_3.z), H2(x##P##_3.z), t0); \
    t1 = __builtin_elementwise_fma(H2(w##r##_3.w), H2(x##P##_3.w), t1); \
    t0 = __builtin_elementwise_fma(H2(w##r##_4.x), H2(x##P##_4.x), t0); \
    t1 = __builtin_elementwise_fma(H2(w##r##_4.y), H2(x##P##_4.y), t1); \
    t0 = __builtin_elementwise_fma(H2(w##r##_4.z), H2(x##P##_4.z), t0); \
    t1 = __builtin_elementwise_fma(H2(w##r##_4.w), H2(x##P##_4.w), t1); \
    t0 = __builtin_elementwise_fma(H2(w##r##_5.x), H2(x##P##_5.x), t0); \
    t1 = __builtin_elementwise_fma(H2(w##r##_5.y), H2(x##P##_5.y), t1); \
    t0 = __builtin_elementwise_fma(H2(w##r##_5.z), H2(x##P##_5.z), t0); \
    t1 = __builtin_elementwise_fma(H2(w##r##_5.w), H2(x##P##_5.w), t1); \
    t0 = __builtin_elementwise_fma(H2(w##r##_6.x), H2(x##P##_6.x), t0); \
    t1 = __builtin_elementwise_fma(H2(w##r##_6.y), H2(x##P##_6.y), t1); \
    t0 = __builtin_elementwise_fma(H2(w##r##_6.z), H2(x##P##_6.z), t0); \
    t1 = __builtin_elementwise_fma(H2(w##r##_6.w), H2(x##P##_6.w), t1); \
    t0 = __builtin_elementwise_fma(H2(w##r##_7.x), H2(x##P##_7.x), t0); \
    t1 = __builtin_elementwise_fma(H2(w##r##_7.y), H2(x##P##_7.y), t1); \
    t0 = __builtin_elementwise_fma(H2(w##r##_7.z), H2(x##P##_7.z), t0); \
    t1 = __builtin_elementwise_fma(H2(w##r##_7.w), H2(x##P##_7.w), t1); \
    acc##P##r = t0 + t1; }

// fallback-kernel helpers (R12-proven)
#define DOT_OCT(j, xv) \
    c00 = __builtin_amdgcn_fdot2(H2(a##j.x), H2((xv).x), c00, false); \
    c01 = __builtin_amdgcn_fdot2(H2(a##j.y), H2((xv).y), c01, false); \
    c02 = __builtin_amdgcn_fdot2(H2(a##j.z), H2((xv).z), c02, false); \
    c03 = __builtin_amdgcn_fdot2(H2(a##j.w), H2((xv).w), c03, false); \
    c10 = __builtin_amdgcn_fdot2(H2(b##j.x), H2((xv).x), c10, false); \
    c11 = __builtin_amdgcn_fdot2(H2(b##j.y), H2((xv).y), c11, false); \
    c12 = __builtin_amdgcn_fdot2(H2(b##j.z), H2((xv).z), c12, false); \
    c13 = __builtin_amdgcn_fdot2(H2(b##j.w), H2((xv).w), c13, false)

#define LDW(j) vu4 a##j, b##j; { \
    const float4* q0 = reinterpret_cast<const float4*>(wr0 + 8 * (j)); \
    const float4* q1 = reinterpret_cast<const float4*>(wr1 + 8 * (j)); \
    float4 f0 = q0[0], f1 = q0[1], g0 = q1[0], g1 = q1[1]; \
    a##j = (vu4){pkh(f0.x, f0.y), pkh(f0.z, f0.w), pkh(f1.x, f1.y), pkh(f1.z, f1.w)}; \
    b##j = (vu4){pkh(g0.x, g0.y), pkh(g0.z, g0.w), pkh(g1.x, g1.y), pkh(g1.z, g1.w)}; }

#define PIN_AB() \
    asm volatile("" : "+v"(a0), "+v"(a1), "+v"(a2),  "+v"(a3), \
                      "+v"(a4), "+v"(a5), "+v"(a6),  "+v"(a7), \
                      "+v"(a8), "+v"(a9), "+v"(a10), "+v"(a11), \
                      "+v"(a12), "+v"(a13), "+v"(a14), "+v"(a15)); \
    asm volatile("" : "+v"(b0), "+v"(b1), "+v"(b2),  "+v"(b3), \
                      "+v"(b4), "+v"(b5), "+v"(b6),  "+v"(b7), \
                      "+v"(b8), "+v"(b9), "+v"(b10), "+v"(b11), \
                      "+v"(b12), "+v"(b13), "+v"(b14), "+v"(b15))

#define PIN_W() \
    asm volatile("" : "+v"(w0_0), "+v"(w0_1), "+v"(w0_2), "+v"(w0_3), \
                      "+v"(w0_4), "+v"(w0_5), "+v"(w0_6), "+v"(w0_7), \
                      "+v"(w1_0), "+v"(w1_1), "+v"(w1_2), "+v"(w1_3), \
                      "+v"(w1_4), "+v"(w1_5), "+v"(w1_6), "+v"(w1_7)); \
    asm volatile("" : "+v"(w2_0), "+v"(w2_1), "+v"(w2_2), "+v"(w2_3), \
                      "+v"(w2_4), "+v"(w2_5), "+v"(w2_6), "+v"(w2_7), \
                      "+v"(w3_0), "+v"(w3_1), "+v"(w3_2), "+v"(w3_3), \
                      "+v"(w3_4), "+v"(w3_5), "+v"(w3_6), "+v"(w3_7))

// ---------------------------------------------------------------------------
// Kernel 0 (R25-proven): drive d = u.W_in + scale*nz + p, packed f16, 4-wide.
// ---------------------------------------------------------------------------
__global__ __launch_bounds__(256) void drive_kernel(
    const float* __restrict__ u,      // [B,T,6]
    const float* __restrict__ p,      // [B,128]
    const float* __restrict__ alpha,  // [1]
    const float* __restrict__ noise,  // [B,T,128]
    const float* __restrict__ W_in,   // [128,6]
    unsigned int* __restrict__ dpre,  // [B*T*64]
    int B, int T)
{
    const float av    = alpha[0];
    const float scale = sqrtf(2.0f * av * SIGMA_REC * SIGMA_REC);
    const size_t total = (size_t)B * T * 32;    // one item = 4 hidden units
    for (size_t idx = (size_t)blockIdx.x * 256 + threadIdx.x; idx < total;
         idx += (size_t)gridDim.x * 256) {
        const int    l  = (int)(idx & 31);      // hidden units 4l..4l+3
        const size_t bt = idx >> 5;
        const int    b  = (int)(bt / (unsigned)T);

        float4 nz = *reinterpret_cast<const float4*>(noise + bt * NH + 4 * l);
        const float2* ur = reinterpret_cast<const float2*>(u + bt * NI);
        float2 ua = ur[0], ub = ur[1], uc = ur[2];
        const float4* wv = reinterpret_cast<const float4*>(W_in + 4 * l * NI);
        float4 g0 = wv[0], g1 = wv[1], g2 = wv[2];
        float4 g3 = wv[3], g4 = wv[4], g5 = wv[5];
        float4 pv = *reinterpret_cast<const float4*>(p + (size_t)b * NH + 4 * l);

        float d0 = fmaf(ua.x, g0.x, fmaf(ua.y, g0.y, fmaf(ub.x, g0.z,
                   fmaf(ub.y, g0.w, fmaf(uc.x, g1.x, fmaf(uc.y, g1.y,
                   fmaf(scale, nz.x, pv.x)))))));
        float d1 = fmaf(ua.x, g1.z, fmaf(ua.y, g1.w, fmaf(ub.x, g2.x,
                   fmaf(ub.y, g2.y, fmaf(uc.x, g2.z, fmaf(uc.y, g2.w,
                   fmaf(scale, nz.y, pv.y)))))));
        float d2 = fmaf(ua.x, g3.x, fmaf(ua.y, g3.y, fmaf(ub.x, g3.z,
                   fmaf(ub.y, g3.w, fmaf(uc.x, g4.x, fmaf(uc.y, g4.y,
                   fmaf(scale, nz.z, pv.z)))))));
        float d3 = fmaf(ua.x, g4.z, fmaf(ua.y, g4.w, fmaf(ub.x, g5.x,
                   fmaf(ub.y, g5.y, fmaf(uc.x, g5.z, fmaf(uc.y, g5.w,
                   fmaf(scale, nz.w, pv.w)))))));

        *reinterpret_cast<uint2*>(dpre + bt * 64 + 2 * l) =
            make_uint2(pkh(d0, d1), pkh(d2, d3));
    }
}

// ---------------------------------------------------------------------------
// R26: DUAL-BATCH chunked speculative scan. One wave runs TWO independent
// batch scans (A = 2bp, B = 2bp+1) with shared W registers. Rationale:
// single-batch waves stall 47% (serial ds_read/shfl/ds_write latency);
// R16 showed 2 waves/SIMD loses to issue contention — software interleave
// inside one wave provides the same latency-filling without arbitration
// and without duplicating W. NCHUNK2=16 keeps 1024 waves (1/SIMD) while
// cutting the critical path 759 -> 572 steps. Per-batch math is VERBATIM
// round-0 (bit-identical states).
// ---------------------------------------------------------------------------
__global__ __attribute__((amdgpu_flat_work_group_size(64, 64),
                          amdgpu_waves_per_eu(1, 2)))
void rnn_scan_pre2(
    const float* __restrict__ W_rec,  // [128,128]
    const unsigned int* __restrict__ dpre,  // [B*T*64]
    float* __restrict__ states,       // [B,T,128]
    const float* __restrict__ alpha,  // [1]
    int T)
{
    const int bp    = blockIdx.x;     // batch pair
    const int chunk = blockIdx.y;
    const int lane  = threadIdx.x;
    const int m     = lane & 31;
    const int h     = lane >> 5;      // k-half
    const int n0    = 4 * m;          // rows n0..n0+3
    const int bA    = 2 * bp, bB = 2 * bp + 1;

    const int NS   = T - 1;                         // 2999 steps total
    const int S    = (NS + NCHUNK2 - 1) / NCHUNK2;  // 188
    const int s0   = chunk * S;
    const int e0   = min(NS, s0 + S);
    if (s0 >= NS) return;
    const int ws   = max(0, s0 - WARM);
    const int NSm1 = NS - 1;

    __shared__ unsigned int xshA[68];   // pairs: half0 @0-31, half1 @36-67
    __shared__ unsigned int xshB[68];

    // ---- W fragments: 4 rows x k-half, shared by both batches ----
    LDWH(0) LDWH(1) LDWH(2) LDWH(3)
    PIN_W();

    const float av  = alpha[0];
    const float oma = 1.0f - av;

    const unsigned int* dA_b = dpre + (size_t)bA * T * 64 + 2 * m;
    const unsigned int* dB_b = dpre + (size_t)bB * T * 64 + 2 * m;
    float* stA = states + (size_t)bA * T * NH + n0;
    float* stB = states + (size_t)bB * T * NH + n0;

    const int pidx  = 2 * m + h;
    const int wslot = pidx + ((pidx >= 32) ? 4 : 0);
    xshA[lane + ((lane >= 32) ? 4 : 0)] = 0u;
    xshB[lane + ((lane >= 32) ? 4 : 0)] = 0u;
    if (chunk == 0 && h == 0) {
        *reinterpret_cast<float4*>(stA) = make_float4(0.f, 0.f, 0.f, 0.f);
        *reinterpret_cast<float4*>(stB) = make_float4(0.f, 0.f, 0.f, 0.f);
    }
    float xoA0 = 0.f, xoA1 = 0.f, xoA2 = 0.f, xoA3 = 0.f;
    float xoB0 = 0.f, xoB1 = 0.f, xoB2 = 0.f, xoB3 = 0.f;

    auto LDA = [&](int t) {
        return *reinterpret_cast<const uint2*>(dA_b + (size_t)t * 64);
    };
    auto LDB = [&](int t) {
        return *reinterpret_cast<const uint2*>(dB_b + (size_t)t * 64);
    };
    const h2v z2 = {(__fp16)0.f, (__fp16)0.f};

    // d-prefetch rings, 8 deep, per batch
    uint2 av0 = LDA(min(ws + 0, NSm1)), av1 = LDA(min(ws + 1, NSm1));
    uint2 av2 = LDA(min(ws + 2, NSm1)), av3 = LDA(min(ws + 3, NSm1));
    uint2 av4 = LDA(min(ws + 4, NSm1)), av5 = LDA(min(ws + 5, NSm1));
    uint2 av6 = LDA(min(ws + 6, NSm1)), av7 = LDA(min(ws + 7, NSm1));
    uint2 bv0 = LDB(min(ws + 0, NSm1)), bv1 = LDB(min(ws + 1, NSm1));
    uint2 bv2 = LDB(min(ws + 2, NSm1)), bv3 = LDB(min(ws + 3, NSm1));
    uint2 bv4 = LDB(min(ws + 4, NSm1)), bv5 = LDB(min(ws + 5, NSm1));
    uint2 bv6 = LDB(min(ws + 6, NSm1)), bv7 = LDB(min(ws + 7, NSm1));

    for (int t = ws; t < e0; ++t) {
        uint2 dnA = LDA(min(t + 8, NSm1));
        uint2 dnB = LDB(min(t + 8, NSm1));

        // ---- batch A compute (B's xh reads issued during A's tail) ----
        const vu4* xrA = reinterpret_cast<const vu4*>(xshA + h * 36);
        vu4 xA_0 = xrA[0], xA_1 = xrA[1], xA_2 = xrA[2], xA_3 = xrA[3];
        vu4 xA_4 = xrA[4], xA_5 = xrA[5], xA_6 = xrA[6], xA_7 = xrA[7];
        ROWDOTP(0, A) ROWDOTP(1, A) ROWDOTP(2, A) ROWDOTP(3, A)
        float fA0 = (float)accA0.x + (float)accA0.y;
        float fA1 = (float)accA1.x + (float)accA1.y;
        float fA2 = (float)accA2.x + (float)accA2.y;
        float fA3 = (float)accA3.x + (float)accA3.y;
        int pkA01 = (int)pkh(fA0, fA1), pkA23 = (int)pkh(fA2, fA3);
        h2v qA01 = H2((unsigned)__shfl_xor(pkA01, 32));
        h2v qA23 = H2((unsigned)__shfl_xor(pkA23, 32));

        // issue B's LDS reads here: they queue behind nothing critical and
        // their latency hides under A's shfl wait + tail
        const vu4* xrB = reinterpret_cast<const vu4*>(xshB + h * 36);
        vu4 xB_0 = xrB[0], xB_1 = xrB[1], xB_2 = xrB[2], xB_3 = xrB[3];
        vu4 xB_4 = xrB[4], xB_5 = xrB[5], xB_6 = xrB[6], xB_7 = xrB[7];

        float sA0 = fA0 + (float)qA01.x, sA1 = fA1 + (float)qA01.y;
        float sA2 = fA2 + (float)qA23.x, sA3 = fA3 + (float)qA23.y;
        h2v hA0 = H2(av0.x), hA1 = H2(av0.y);
        float xnA0 = fmaf(oma, xoA0, av * fmaxf(sA0 + (float)hA0.x, 0.f));
        float xnA1 = fmaf(oma, xoA1, av * fmaxf(sA1 + (float)hA0.y, 0.f));
        float xnA2 = fmaf(oma, xoA2, av * fmaxf(sA2 + (float)hA1.x, 0.f));
        float xnA3 = fmaf(oma, xoA3, av * fmaxf(sA3 + (float)hA1.y, 0.f));
        xoA0 = xnA0; xoA1 = xnA1; xoA2 = xnA2; xoA3 = xnA3;
        if (t >= s0 && h == 0) {
            *reinterpret_cast<float4*>(stA + (size_t)(t + 1) * NH) =
                make_float4(xnA0, xnA1, xnA2, xnA3);
        }
        xshA[wslot] = h ? pkh(xnA2, xnA3) : pkh(xnA0, xnA1);

        // ---- batch B compute (fills A's residual latency) ----
        ROWDOTP(0, B) ROWDOTP(1, B) ROWDOTP(2, B) ROWDOTP(3, B)
        float fB0 = (float)accB0.x + (float)accB0.y;
        float fB1 = (float)accB1.x + (float)accB1.y;
        float fB2 = (float)accB2.x + (float)accB2.y;
        float fB3 = (float)accB3.x + (float)accB3.y;
        int pkB01 = (int)pkh(fB0, fB1), pkB23 = (int)pkh(fB2, fB3);
        h2v qB01 = H2((unsigned)__shfl_xor(pkB01, 32));
        h2v qB23 = H2((unsigned)__shfl_xor(pkB23, 32));
        float sB0 = fB0 + (float)qB01.x, sB1 = fB1 + (float)qB01.y;
        float sB2 = fB2 + (float)qB23.x, sB3 = fB3 + (float)qB23.y;
        h2v hB0 = H2(bv0.x), hB1 = H2(bv0.y);
        float xnB0 = fmaf(oma, xoB0, av * fmaxf(sB0 + (float)hB0.x, 0.f));
        float xnB1 = fmaf(oma, xoB1, av * fmaxf(sB1 + (float)hB0.y, 0.f));
        float xnB2 = fmaf(oma, xoB2, av * fmaxf(sB2 + (float)hB1.x, 0.f));
        float xnB3 = fmaf(oma, xoB3, av * fmaxf(sB3 + (float)hB1.y, 0.f));
        xoB0 = xnB0; xoB1 = xnB1; xoB2 = xnB2; xoB3 = xnB3;
        if (t >= s0 && h == 0) {
            *reinterpret_cast<float4*>(stB + (size_t)(t + 1) * NH) =
                make_float4(xnB0, xnB1, xnB2, xnB3);
        }
        xshB[wslot] = h ? pkh(xnB2, xnB3) : pkh(xnB0, xnB1);

        // rotate rings
        av0 = av1; av1 = av2; av2 = av3; av3 = av4;
        av4 = av5; av5 = av6; av6 = av7; av7 = dnA;
        bv0 = bv1; bv1 = bv2; bv2 = bv3; bv3 = bv4;
        bv4 = bv5; bv5 = bv6; bv6 = bv7; bv7 = dnB;
    }
}

// ---------------------------------------------------------------------------
// Single-batch scan (round-0 proven, verbatim math): used if B is odd.
// ---------------------------------------------------------------------------
__global__ __attribute__((amdgpu_flat_work_group_size(64, 64),
                          amdgpu_waves_per_eu(1, 2)))
void rnn_scan_pre(
    const float* __restrict__ W_rec,  // [128,128]
    const unsigned int* __restrict__ dpre,  // [B*T*64]
    float* __restrict__ states,       // [B,T,128]
    const float* __restrict__ alpha,  // [1]
    int T)
{
    const int b     = blockIdx.x;
    const int chunk = blockIdx.y;
    const int lane  = threadIdx.x;
    const int m     = lane & 31;
    const int h     = lane >> 5;      // k-half
    const int n0    = 4 * m;          // rows n0..n0+3

    const int NS   = T - 1;                       // 2999 steps total
    const int S    = (NS + NCHUNK - 1) / NCHUNK;  // 375
    const int s0   = chunk * S;
    const int e0   = min(NS, s0 + S);
    if (s0 >= NS) return;
    const int ws   = max(0, s0 - WARM);
    const int NSm1 = NS - 1;

    __shared__ unsigned int xshA[68];   // pairs: half0 @0-31, half1 @36-67

    LDWH(0) LDWH(1) LDWH(2) LDWH(3)
    PIN_W();

    const float av  = alpha[0];
    const float oma = 1.0f - av;

    const unsigned int* d_b = dpre + (size_t)b * T * 64 + 2 * m;
    float* states_b = states + (size_t)b * T * NH + n0;

    const int pidx  = 2 * m + h;
    const int wslot = pidx + ((pidx >= 32) ? 4 : 0);
    xshA[lane + ((lane >= 32) ? 4 : 0)] = 0u;
    if (chunk == 0 && h == 0) {
        *reinterpret_cast<float4*>(states_b) = make_float4(0.f, 0.f, 0.f, 0.f);
    }
    float xoA0 = 0.f, xoA1 = 0.f, xoA2 = 0.f, xoA3 = 0.f;

    auto LDD = [&](int t) {
        return *reinterpret_cast<const uint2*>(d_b + (size_t)t * 64);
    };
    const h2v z2 = {(__fp16)0.f, (__fp16)0.f};

    uint2 av0 = LDD(min(ws + 0, NSm1)), av1 = LDD(min(ws + 1, NSm1));
    uint2 av2 = LDD(min(ws + 2, NSm1)), av3 = LDD(min(ws + 3, NSm1));
    uint2 av4 = LDD(min(ws + 4, NSm1)), av5 = LDD(min(ws + 5, NSm1));
    uint2 av6 = LDD(min(ws + 6, NSm1)), av7 = LDD(min(ws + 7, NSm1));

    for (int t = ws; t < e0; ++t) {
        uint2 dn = LDD(min(t + 8, NSm1));
        const vu4* xrA = reinterpret_cast<const vu4*>(xshA + h * 36);
        vu4 xA_0 = xrA[0], xA_1 = xrA[1], xA_2 = xrA[2], xA_3 = xrA[3];
        vu4 xA_4 = xrA[4], xA_5 = xrA[5], xA_6 = xrA[6], xA_7 = xrA[7];
        ROWDOTP(0, A) ROWDOTP(1, A) ROWDOTP(2, A) ROWDOTP(3, A)
        float f0 = (float)accA0.x + (float)accA0.y;
        float f1 = (float)accA1.x + (float)accA1.y;
        float f2 = (float)accA2.x + (float)accA2.y;
        float f3 = (float)accA3.x + (float)accA3.y;
        int pk01 = (int)pkh(f0, f1), pk23 = (int)pkh(f2, f3);
        h2v q01 = H2((unsigned)__shfl_xor(pk01, 32));
        h2v q23 = H2((unsigned)__shfl_xor(pk23, 32));
        float s0v = f0 + (float)q01.x, s1v = f1 + (float)q01.y;
        float s2v = f2 + (float)q23.x, s3v = f3 + (float)q23.y;
        h2v hd0 = H2(av0.x), hd1 = H2(av0.y);
        float xn0 = fmaf(oma, xoA0, av * fmaxf(s0v + (float)hd0.x, 0.f));
        float xn1 = fmaf(oma, xoA1, av * fmaxf(s1v + (float)hd0.y, 0.f));
        float xn2 = fmaf(oma, xoA2, av * fmaxf(s2v + (float)hd1.x, 0.f));
        float xn3 = fmaf(oma, xoA3, av * fmaxf(s3v + (float)hd1.y, 0.f));
        xoA0 = xn0; xoA1 = xn1; xoA2 = xn2; xoA3 = xn3;
        if (t >= s0 && h == 0) {
            *reinterpret_cast<float4*>(states_b + (size_t)(t + 1) * NH) =
                make_float4(xn0, xn1, xn2, xn3);
        }
        xshA[wslot] = h ? pkh(xn2, xn3) : pkh(xn0, xn1);
        av0 = av1; av1 = av2; av2 = av3; av3 = av4;
        av4 = av5; av5 = av6; av6 = av7; av7 = dn;
    }
}

// ---------------------------------------------------------------------------
// Fallback scan (R12 verbatim, exact, non-chunked): if ws_size too small.
// ---------------------------------------------------------------------------
__global__ __attribute__((amdgpu_flat_work_group_size(64, 64),
                          amdgpu_waves_per_eu(1, 1)))
void rnn_scan_fb(
    const float* __restrict__ u, const float* __restrict__ p,
    const float* __restrict__ alpha, const float* __restrict__ noise,
    const float* __restrict__ W_rec, const float* __restrict__ W_in,
    float* __restrict__ states, int T)
{
    const int b    = blockIdx.x;
    const int lane = threadIdx.x;
    const int n0   = lane * 2;

    __shared__ unsigned int xsh[64];

    const float* wr0 = W_rec + (size_t)n0 * NH;
    const float* wr1 = wr0 + NH;
    LDW(0)  LDW(1)  LDW(2)  LDW(3)  LDW(4)  LDW(5)  LDW(6)  LDW(7)
    LDW(8)  LDW(9)  LDW(10) LDW(11) LDW(12) LDW(13) LDW(14) LDW(15)
    PIN_AB();

    const float wiA0 = W_in[n0 * NI + 0], wiA1 = W_in[n0 * NI + 1];
    const float wiA2 = W_in[n0 * NI + 2], wiA3 = W_in[n0 * NI + 3];
    const float wiA4 = W_in[n0 * NI + 4], wiA5 = W_in[n0 * NI + 5];
    const float wiB0 = W_in[(n0 + 1) * NI + 0], wiB1 = W_in[(n0 + 1) * NI + 1];
    const float wiB2 = W_in[(n0 + 1) * NI + 2], wiB3 = W_in[(n0 + 1) * NI + 3];
    const float wiB4 = W_in[(n0 + 1) * NI + 4], wiB5 = W_in[(n0 + 1) * NI + 5];

    const float2 pn   = *reinterpret_cast<const float2*>(p + (size_t)b * NH + n0);
    const float av    = alpha[0];
    const float oma   = 1.0f - av;
    const float scale = sqrtf(2.0f * av * SIGMA_REC * SIGMA_REC);

    const float* noise_b = noise + (size_t)b * T * NH + n0;
    unsigned int zv;
    asm volatile("v_mov_b32 %0, 0" : "=v"(zv));
    const float* u_b = u + (size_t)b * T * NI + zv;
    float* st_ptr = states + (size_t)b * T * NH + n0 + NH;

    xsh[lane] = 0u;
    *reinterpret_cast<float2*>(states + (size_t)b * T * NH + n0) = make_float2(0.f, 0.f);
    float xo0 = 0.0f, xo1 = 0.0f;

    auto LDnz = [&](int t) {
        return *reinterpret_cast<const float2*>(noise_b + (size_t)t * NH);
    };
    auto loadU = [&](int t) {
        const float2* up = reinterpret_cast<const float2*>(u_b + (size_t)t * NI);
        U6 r; r.a = up[0]; r.b = up[1]; r.c = up[2]; return r;
    };
    auto mkd = [&](float2 nz, const U6& uu) {
        float dx = fmaf(uu.a.x, wiA0, fmaf(uu.a.y, wiA1, fmaf(uu.b.x, wiA2,
                   fmaf(uu.b.y, wiA3, fmaf(uu.c.x, wiA4, fmaf(uu.c.y, wiA5,
                   fmaf(scale, nz.x, pn.x)))))));
        float dy = fmaf(uu.a.x, wiB0, fmaf(uu.a.y, wiB1, fmaf(uu.b.x, wiB2,
                   fmaf(uu.b.y, wiB3, fmaf(uu.c.x, wiB4, fmaf(uu.c.y, wiB5,
                   fmaf(scale, nz.y, pn.y)))))));
        return make_float2(dx, dy);
    };
    auto step = [&](float2 d) {
        const vu4* xr = reinterpret_cast<const vu4*>(xsh);
        float c00 = 0.f, c01 = 0.f, c02 = 0.f, c03 = 0.f;
        float c10 = 0.f, c11 = 0.f, c12 = 0.f, c13 = 0.f;
        vu4 xv0 = xr[0], xv1 = xr[1], xv2 = xr[2], xv3 = xr[3];
        vu4 xv4 = xr[4], xv5 = xr[5], xv6 = xr[6], xv7 = xr[7];
        DOT_OCT(0, xv0);  DOT_OCT(1, xv1);  DOT_OCT(2, xv2);  DOT_OCT(3, xv3);
        vu4 xv8 = xr[8], xv9 = xr[9], xv10 = xr[10], xv11 = xr[11];
        DOT_OCT(4, xv4);  DOT_OCT(5, xv5);  DOT_OCT(6, xv6);  DOT_OCT(7, xv7);
        vu4 xv12 = xr[12], xv13 = xr[13], xv14 = xr[14], xv15 = xr[15];
        DOT_OCT(8, xv8);  DOT_OCT(9, xv9);  DOT_OCT(10, xv10); DOT_OCT(11, xv11);
        DOT_OCT(12, xv12); DOT_OCT(13, xv13); DOT_OCT(14, xv14); DOT_OCT(15, xv15);
        float pre0 = ((c00 + c01) + (c02 + c03)) + d.x;
        float pre1 = ((c10 + c11) + (c12 + c13)) + d.y;
        float xn0 = fmaf(oma, xo0, av * fmaxf(pre0, 0.f));
        float xn1 = fmaf(oma, xo1, av * fmaxf(pre1, 0.f));
        xo0 = xn0; xo1 = xn1;
        *reinterpret_cast<float2*>(st_ptr) = make_float2(xn0, xn1);
        st_ptr += NH;
        xsh[lane] = pkh(xn0, xn1);
    };

    float2 nz0 = LDnz(0), nz1 = LDnz(1), nz2 = LDnz(2), nz3 = LDnz(3);
    U6 u0 = loadU(0), u1 = loadU(1), u2 = loadU(2), u3 = loadU(3);
    float2 nzA0 = LDnz(4), nzA1 = LDnz(5);   U6 uA0 = loadU(4), uA1 = loadU(5);
    float2 nzB0 = LDnz(6), nzB1 = LDnz(7);   U6 uB0 = loadU(6), uB1 = loadU(7);
    float2 d0 = mkd(nz0, u0), d1 = mkd(nz1, u1);
    float2 d2 = mkd(nz2, u2), d3 = mkd(nz3, u3);

    int t = 0;
    for (; t + 1 < T - 1; t += 2) {
        const int t8 = min(t + 8, T - 1), t9 = min(t + 9, T - 1);
        float2 nzC0 = LDnz(t8), nzC1 = LDnz(t9);
        U6 uC0 = loadU(t8), uC1 = loadU(t9);
        float2 dE = mkd(nzA0, uA0), dF = mkd(nzA1, uA1);
        step(d0);
        step(d1);
        d0 = d2; d1 = d3; d2 = dE; d3 = dF;
        nzA0 = nzB0; nzA1 = nzB1; uA0 = uB0; uA1 = uB1;
        nzB0 = nzC0; nzB1 = nzC1; uB0 = uC0; uB1 = uC1;
    }
    if (t < T - 1) step(d0);
}

// ---------------------------------------------------------------------------
// Projection: out[r,o] = sum_n relu(states[r,n]) * W_out[o,n]
// ---------------------------------------------------------------------------
__global__ __launch_bounds__(256) void out_proj_kernel(
    const float* __restrict__ states,  // [rows,128]
    const float* __restrict__ W_out,   // [2,128]
    float* __restrict__ out,           // [rows,2]
    int rows)
{
    const int wave = threadIdx.x >> 6;
    const int lane = threadIdx.x & 63;
    const int l    = lane & 31;
    const int row  = blockIdx.x * 8 + wave * 2 + (lane >> 5);
    if (row >= rows) return;

    float4 s = *reinterpret_cast<const float4*>(states + (size_t)row * NH + l * 4);
    s.x = fmaxf(s.x, 0.f); s.y = fmaxf(s.y, 0.f);
    s.z = fmaxf(s.z, 0.f); s.w = fmaxf(s.w, 0.f);
    float4 wa = reinterpret_cast<const float4*>(W_out)[l];
    float4 wb = reinterpret_cast<const float4*>(W_out + NH)[l];
    float c0 = s.x * wa.x + s.y * wa.y + s.z * wa.z + s.w * wa.w;
    float c1 = s.x * wb.x + s.y * wb.y + s.z * wb.z + s.w * wb.w;

#pragma unroll
    for (int off = 16; off >= 1; off >>= 1) {
        c0 += __shfl_xor(c0, off);
        c1 += __shfl_xor(c1, off);
    }
    if (l == 0) {
        *reinterpret_cast<float2*>(out + (size_t)row * 2) = make_float2(c0, c1);
    }
}

// ---------------------------------------------------------------------------
extern "C" void kernel_launch(void* const* d_in, const int* in_sizes, int n_in,
                              void* d_out, int out_size, void* d_ws, size_t ws_size,
                              hipStream_t stream) {
    const float* u     = (const float*)d_in[0];
    const float* p     = (const float*)d_in[1];
    const float* alpha = (const float*)d_in[2];
    const float* noise = (const float*)d_in[3];
    const float* W_rec = (const float*)d_in[4];
    const float* W_in  = (const float*)d_in[5];
    const float* W_out = (const float*)d_in[6];

    const int B = in_sizes[1] / NH;           // 128
    const int T = in_sizes[0] / (B * NI);     // 3000

    float* out    = (float*)d_out;                    // [B,T,2]
    float* states = out + (size_t)B * T * 2;          // [B,T,128]

    const size_t need = (size_t)B * T * 64 * sizeof(unsigned int);  // 98.3 MB
    if (d_ws != nullptr && ws_size >= need) {
        unsigned int* dpre = (unsigned int*)d_ws;
        drive_kernel<<<2048, 256, 0, stream>>>(u, p, alpha, noise, W_in,
                                               dpre, B, T);
        if ((B % 2) == 0) {
            dim3 grid(B / 2, NCHUNK2);
            rnn_scan_pre2<<<grid, 64, 0, stream>>>(W_rec, dpre, states,
                                                   alpha, T);
        } else {
            dim3 grid(B, NCHUNK);
            rnn_scan_pre<<<grid, 64, 0, stream>>>(W_rec, dpre, states,
                                                  alpha, T);
        }
    } else {
        rnn_scan_fb<<<B, 64, 0, stream>>>(u, p, alpha, noise, W_rec, W_in,
                                          states, T);
    }

    const int rows = B * T;
    out_proj_kernel<<<(rows + 7) / 8, 256, 0, stream>>>(states, W_out, out, rows);
}

// Round 11
// 518.822 us; speedup vs baseline: 1.2025x; 1.2025x over previous
//
#include <hip/hip_runtime.h>
#include <math.h>

#define NH 128          // hidden size
#define NI 6            // input size
#define SIGMA_REC 0.15f
#define NCHUNK 8        // speculative chunks per batch row (R17: 16 -> 8;
                        // per-CU wave-steps = 0.5*(NCHUNK*WARM + NS) -> -34%,
                        // and 4 waves/CU = 1 wave/SIMD kills VALU contention)
#define WARM 384        // warmup steps (R16/R17: absmax at 384 == f16 floor)

typedef __fp16 h2v __attribute__((ext_vector_type(2)));
typedef unsigned int vu4 __attribute__((ext_vector_type(4)));

__device__ __forceinline__ unsigned int pkh(float a, float b) {
    h2v h = __builtin_amdgcn_cvt_pkrtz(a, b);   // pack 2 f32 -> 2 f16 (RTZ)
    return __builtin_bit_cast(unsigned int, h);
}
#define H2(u) __builtin_bit_cast(h2v, (unsigned int)(u))

struct U6 { float2 a, b, c; };

// ---- load+pack one row's k-half of W: row n0+r, k in [64h, 64h+64) ----
#define LDWH(r) vu4 w##r##_0, w##r##_1, w##r##_2, w##r##_3, \
                    w##r##_4, w##r##_5, w##r##_6, w##r##_7; { \
    const float4* qp = reinterpret_cast<const float4*>( \
        W_rec + (size_t)(n0 + (r)) * NH + 64 * h); \
    float4 f0 = qp[0],  f1 = qp[1],  f2 = qp[2],  f3 = qp[3]; \
    float4 f4 = qp[4],  f5 = qp[5],  f6 = qp[6],  f7 = qp[7]; \
    float4 f8 = qp[8],  f9 = qp[9],  fA = qp[10], fB = qp[11]; \
    float4 fC = qp[12], fD = qp[13], fE = qp[14], fF = qp[15]; \
    w##r##_0 = (vu4){pkh(f0.x,f0.y), pkh(f0.z,f0.w), pkh(f1.x,f1.y), pkh(f1.z,f1.w)}; \
    w##r##_1 = (vu4){pkh(f2.x,f2.y), pkh(f2.z,f2.w), pkh(f3.x,f3.y), pkh(f3.z,f3.w)}; \
    w##r##_2 = (vu4){pkh(f4.x,f4.y), pkh(f4.z,f4.w), pkh(f5.x,f5.y), pkh(f5.z,f5.w)}; \
    w##r##_3 = (vu4){pkh(f6.x,f6.y), pkh(f6.z,f6.w), pkh(f7.x,f7.y), pkh(f7.z,f7.w)}; \
    w##r##_4 = (vu4){pkh(f8.x,f8.y), pkh(f8.z,f8.w), pkh(f9.x,f9.y), pkh(f9.z,f9.w)}; \
    w##r##_5 = (vu4){pkh(fA.x,fA.y), pkh(fA.z,fA.w), pkh(fB.x,fB.y), pkh(fB.z,fB.w)}; \
    w##r##_6 = (vu4){pkh(fC.x,fC.y), pkh(fC.z,fC.w), pkh(fD.x,fD.y), pkh(fD.z,fD.w)}; \
    w##r##_7 = (vu4){pkh(fE.x,fE.y), pkh(fE.z,fE.w), pkh(fF.x,fF.y), pkh(fF.z,fF.w)}; }

// ---- 32 pk_fma (2 chains of 16): row r's partial dot over this k-half ----
#define ROWDOT(r) h2v acc##r; { \
    h2v t0 = __builtin_elementwise_fma(H2(w##r##_0.x), H2(xh0.x), z2); \
    h2v t1 = __builtin_elementwise_fma(H2(w##r##_0.y), H2(xh0.y), z2); \
    t0 = __builtin_elementwise_fma(H2(w##r##_0.z), H2(xh0.z), t0); \
    t1 = __builtin_elementwise_fma(H2(w##r##_0.w), H2(xh0.w), t1); \
    t0 = __builtin_elementwise_fma(H2(w##r##_1.x), H2(xh1.x), t0); \
    t1 = __builtin_elementwise_fma(H2(w##r##_1.y), H2(xh1.y), t1); \
    t0 = __builtin_elementwise_fma(H2(w##r##_1.z), H2(xh1.z), t0); \
    t1 = __builtin_elementwise_fma(H2(w##r##_1.w), H2(xh1.w), t1); \
    t0 = __builtin_elementwise_fma(H2(w##r##_2.x), H2(xh2.x), t0); \
    t1 = __builtin_elementwise_fma(H2(w##r##_2.y), H2(xh2.y), t1); \
    t0 = __builtin_elementwise_fma(H2(w##r##_2.z), H2(xh2.z), t0); \
    t1 = __builtin_elementwise_fma(H2(w##r##_2.w), H2(xh2.w), t1); \
    t0 = __builtin_elementwise_fma(H2(w##r##_3.x), H2(xh3.x), t0); \
    t1 = __builtin_elementwise_fma(H2(w##r##_3.y), H2(xh3.y), t1); \
    t0 = __builtin_elementwise_fma(H2(w##r##_3.z), H2(xh3.z), t0); \
    t1 = __builtin_elementwise_fma(H2(w##r##_3.w), H2(xh3.w), t1); \
    t0 = __builtin_elementwise_fma(H2(w##r##_4.x), H2(xh4.x), t0); \
    t1 = __builtin_elementwise_fma(H2(w##r##_4.y), H2(xh4.y), t1); \
    t0 = __builtin_elementwise_fma(H2(w##r##_4.z), H2(xh4.z), t0); \
    t1 = __builtin_elementwise_fma(H2(w##r##_4.w), H2(xh4.w), t1); \
    t0 = __builtin_elementwise_fma(H2(w##r##_5.x), H2(xh5.x), t0); \
    t1 = __builtin_elementwise_fma(H2(w##r##_5.y), H2(xh5.y), t1); \
    t0 = __builtin_elementwise_fma(H2(w##r##_5.z), H2(xh5.z), t0); \
    t1 = __builtin_elementwise_fma(H2(w##r##_5.w), H2(xh5.w), t1); \
    t0 = __builtin_elementwise_fma(H2(w##r##_6.x), H2(xh6.x), t0); \
    t1 = __builtin_elementwise_fma(H2(w##r##_6.y), H2(xh6.y), t1); \
    t0 = __builtin_elementwise_fma(H2(w##r##_6.z), H2(xh6.z), t0); \
    t1 = __builtin_elementwise_fma(H2(w##r##_6.w), H2(xh6.w), t1); \
    t0 = __builtin_elementwise_fma(H2(w##r##_7.x), H2(xh7.x), t0); \
    t1 = __builtin_elementwise_fma(H2(w##r##_7.y), H2(xh7.y), t1); \
    t0 = __builtin_elementwise_fma(H2(w##r##_7.z), H2(xh7.z), t0); \
    t1 = __builtin_elementwise_fma(H2(w##r##_7.w), H2(xh7.w), t1); \
    acc##r = t0 + t1; }

// fallback-kernel helpers (R12-proven)
#define DOT_OCT(j, xv) \
    c00 = __builtin_amdgcn_fdot2(H2(a##j.x), H2((xv).x), c00, false); \
    c01 = __builtin_amdgcn_fdot2(H2(a##j.y), H2((xv).y), c01, false); \
    c02 = __builtin_amdgcn_fdot2(H2(a##j.z), H2((xv).z), c02, false); \
    c03 = __builtin_amdgcn_fdot2(H2(a##j.w), H2((xv).w), c03, false); \
    c10 = __builtin_amdgcn_fdot2(H2(b##j.x), H2((xv).x), c10, false); \
    c11 = __builtin_amdgcn_fdot2(H2(b##j.y), H2((xv).y), c11, false); \
    c12 = __builtin_amdgcn_fdot2(H2(b##j.z), H2((xv).z), c12, false); \
    c13 = __builtin_amdgcn_fdot2(H2(b##j.w), H2((xv).w), c13, false)

#define LDW(j) vu4 a##j, b##j; { \
    const float4* q0 = reinterpret_cast<const float4*>(wr0 + 8 * (j)); \
    const float4* q1 = reinterpret_cast<const float4*>(wr1 + 8 * (j)); \
    float4 f0 = q0[0], f1 = q0[1], g0 = q1[0], g1 = q1[1]; \
    a##j = (vu4){pkh(f0.x, f0.y), pkh(f0.z, f0.w), pkh(f1.x, f1.y), pkh(f1.z, f1.w)}; \
    b##j = (vu4){pkh(g0.x, g0.y), pkh(g0.z, g0.w), pkh(g1.x, g1.y), pkh(g1.z, g1.w)}; }

#define PIN_AB() \
    asm volatile("" : "+v"(a0), "+v"(a1), "+v"(a2),  "+v"(a3), \
                      "+v"(a4), "+v"(a5), "+v"(a6),  "+v"(a7), \
                      "+v"(a8), "+v"(a9), "+v"(a10), "+v"(a11), \
                      "+v"(a12), "+v"(a13), "+v"(a14), "+v"(a15)); \
    asm volatile("" : "+v"(b0), "+v"(b1), "+v"(b2),  "+v"(b3), \
                      "+v"(b4), "+v"(b5), "+v"(b6),  "+v"(b7), \
                      "+v"(b8), "+v"(b9), "+v"(b10), "+v"(b11), \
                      "+v"(b12), "+v"(b13), "+v"(b14), "+v"(b15))

// ---------------------------------------------------------------------------
// Kernel 0 (R25): drive d[b,t,n] = u.W_in + scale*nz + p, packed f16.
// 4-wide: one thread per 4 hidden units -> float4 noise load (16B/lane),
// 6x float4 W_in (L1-resident), uint2 packed store. fma chain in IDENTICAL
// association order as round-0 -> bit-identical dpre.
// ---------------------------------------------------------------------------
__global__ __launch_bounds__(256) void drive_kernel(
    const float* __restrict__ u,      // [B,T,6]
    const float* __restrict__ p,      // [B,128]
    const float* __restrict__ alpha,  // [1]
    const float* __restrict__ noise,  // [B,T,128]
    const float* __restrict__ W_in,   // [128,6]
    unsigned int* __restrict__ dpre,  // [B*T*64]
    int B, int T)
{
    const float av    = alpha[0];
    const float scale = sqrtf(2.0f * av * SIGMA_REC * SIGMA_REC);
    const size_t total = (size_t)B * T * 32;    // one item = 4 hidden units
    for (size_t idx = (size_t)blockIdx.x * 256 + threadIdx.x; idx < total;
         idx += (size_t)gridDim.x * 256) {
        const int    l  = (int)(idx & 31);      // hidden units 4l..4l+3
        const size_t bt = idx >> 5;
        const int    b  = (int)(bt / (unsigned)T);

        float4 nz = *reinterpret_cast<const float4*>(noise + bt * NH + 4 * l);
        const float2* ur = reinterpret_cast<const float2*>(u + bt * NI);
        float2 ua = ur[0], ub = ur[1], uc = ur[2];
        // W_in rows 4l..4l+3 = 24 contiguous floats = 6 float4 (96B-aligned)
        const float4* wv = reinterpret_cast<const float4*>(W_in + 4 * l * NI);
        float4 g0 = wv[0], g1 = wv[1], g2 = wv[2];
        float4 g3 = wv[3], g4 = wv[4], g5 = wv[5];
        float4 pv = *reinterpret_cast<const float4*>(p + (size_t)b * NH + 4 * l);

        // row 0: {g0.x g0.y g0.z g0.w g1.x g1.y}
        float d0 = fmaf(ua.x, g0.x, fmaf(ua.y, g0.y, fmaf(ub.x, g0.z,
                   fmaf(ub.y, g0.w, fmaf(uc.x, g1.x, fmaf(uc.y, g1.y,
                   fmaf(scale, nz.x, pv.x)))))));
        // row 1: {g1.z g1.w g2.x g2.y g2.z g2.w}
        float d1 = fmaf(ua.x, g1.z, fmaf(ua.y, g1.w, fmaf(ub.x, g2.x,
                   fmaf(ub.y, g2.y, fmaf(uc.x, g2.z, fmaf(uc.y, g2.w,
                   fmaf(scale, nz.y, pv.y)))))));
        // row 2: {g3.x g3.y g3.z g3.w g4.x g4.y}
        float d2 = fmaf(ua.x, g3.x, fmaf(ua.y, g3.y, fmaf(ub.x, g3.z,
                   fmaf(ub.y, g3.w, fmaf(uc.x, g4.x, fmaf(uc.y, g4.y,
                   fmaf(scale, nz.z, pv.z)))))));
        // row 3: {g4.z g4.w g5.x g5.y g5.z g5.w}
        float d3 = fmaf(ua.x, g4.z, fmaf(ua.y, g4.w, fmaf(ub.x, g5.x,
                   fmaf(ub.y, g5.y, fmaf(uc.x, g5.z, fmaf(uc.y, g5.w,
                   fmaf(scale, nz.w, pv.w)))))));

        *reinterpret_cast<uint2*>(dpre + bt * 64 + 2 * l) =
            make_uint2(pkh(d0, d1), pkh(d2, d3));
    }
}

// ---------------------------------------------------------------------------
// Chunked speculative scan, HALF-k split — ROUND-0 PROVEN KERNEL, VERBATIM.
// Session post-mortems (R18-R26): MFMA batching (4 variants) d-stream-bound;
// projection fusion (2 placements) and dual-batch interleave DS-queue-bound
// (per-wave DS pipe is in-order — ANY added DS ops cost 2-4x modeled work);
// 2 waves/SIMD issue-bound (R16). This configuration is the measured optimum.
// ---------------------------------------------------------------------------
__global__ __attribute__((amdgpu_flat_work_group_size(64, 64),
                          amdgpu_waves_per_eu(1, 2)))
void rnn_scan_pre(
    const float* __restrict__ W_rec,  // [128,128]
    const unsigned int* __restrict__ dpre,  // [B*T*64]
    float* __restrict__ states,       // [B,T,128]
    const float* __restrict__ alpha,  // [1]
    int T)
{
    const int b     = blockIdx.x;
    const int chunk = blockIdx.y;
    const int lane  = threadIdx.x;
    const int m     = lane & 31;
    const int h     = lane >> 5;      // k-half
    const int n0    = 4 * m;          // rows n0..n0+3

    const int NS   = T - 1;                       // 2999 steps total
    const int S    = (NS + NCHUNK - 1) / NCHUNK;  // 375
    const int s0   = chunk * S;
    const int e0   = min(NS, s0 + S);
    if (s0 >= NS) return;
    const int ws   = max(0, s0 - WARM);
    const int NSm1 = NS - 1;

    __shared__ unsigned int xsh[68];   // pairs: half0 @0-31, half1 @36-67

    // ---- W fragments: 4 rows x k-half, 32 named vu4 (128 dwords) ----
    LDWH(0) LDWH(1) LDWH(2) LDWH(3)
    asm volatile("" : "+v"(w0_0), "+v"(w0_1), "+v"(w0_2), "+v"(w0_3),
                      "+v"(w0_4), "+v"(w0_5), "+v"(w0_6), "+v"(w0_7),
                      "+v"(w1_0), "+v"(w1_1), "+v"(w1_2), "+v"(w1_3),
                      "+v"(w1_4), "+v"(w1_5), "+v"(w1_6), "+v"(w1_7));
    asm volatile("" : "+v"(w2_0), "+v"(w2_1), "+v"(w2_2), "+v"(w2_3),
                      "+v"(w2_4), "+v"(w2_5), "+v"(w2_6), "+v"(w2_7),
                      "+v"(w3_0), "+v"(w3_1), "+v"(w3_2), "+v"(w3_3),
                      "+v"(w3_4), "+v"(w3_5), "+v"(w3_6), "+v"(w3_7));

    const float av  = alpha[0];
    const float oma = 1.0f - av;

    const unsigned int* d_b = dpre + (size_t)b * T * 64 + 2 * m;  // pairs 2m,2m+1
    float* states_b = states + (size_t)b * T * NH + n0;

    // LDS write slot: h=0 writes pair 2m, h=1 writes pair 2m+1 (+4 pad if >=32)
    const int pidx  = 2 * m + h;
    const int wslot = pidx + ((pidx >= 32) ? 4 : 0);
    xsh[lane + ((lane >= 32) ? 4 : 0)] = 0u;    // zero all 64 data slots
    if (chunk == 0 && h == 0) {
        *reinterpret_cast<float4*>(states_b) = make_float4(0.f, 0.f, 0.f, 0.f);
    }
    float xo0 = 0.f, xo1 = 0.f, xo2 = 0.f, xo3 = 0.f;

    auto LDD = [&](int t) {
        return *reinterpret_cast<const uint2*>(d_b + (size_t)t * 64);
    };
    const h2v z2 = {(__fp16)0.f, (__fp16)0.f};

    // d-prefetch ring, 8 deep
    uint2 dv0 = LDD(min(ws + 0, NSm1)), dv1 = LDD(min(ws + 1, NSm1));
    uint2 dv2 = LDD(min(ws + 2, NSm1)), dv3 = LDD(min(ws + 3, NSm1));
    uint2 dv4 = LDD(min(ws + 4, NSm1)), dv5 = LDD(min(ws + 5, NSm1));
    uint2 dv6 = LDD(min(ws + 6, NSm1)), dv7 = LDD(min(ws + 7, NSm1));

    for (int t = ws; t < e0; ++t) {
        uint2 dn = LDD(min(t + 8, NSm1));
        // ---- one step using dv0 ----
        const vu4* xr = reinterpret_cast<const vu4*>(xsh + h * 36);
        vu4 xh0 = xr[0], xh1 = xr[1], xh2 = xr[2], xh3 = xr[3];
        vu4 xh4 = xr[4], xh5 = xr[5], xh6 = xr[6], xh7 = xr[7];
        ROWDOT(0) ROWDOT(1) ROWDOT(2) ROWDOT(3)
        // partial sums -> f32, pack, exchange with other k-half (2 shfl)
        float f0 = (float)acc0.x + (float)acc0.y;
        float f1 = (float)acc1.x + (float)acc1.y;
        float f2 = (float)acc2.x + (float)acc2.y;
        float f3 = (float)acc3.x + (float)acc3.y;
        int pk01 = (int)pkh(f0, f1), pk23 = (int)pkh(f2, f3);
        h2v q01 = H2((unsigned)__shfl_xor(pk01, 32));
        h2v q23 = H2((unsigned)__shfl_xor(pk23, 32));
        float s0v = f0 + (float)q01.x, s1v = f1 + (float)q01.y;
        float s2v = f2 + (float)q23.x, s3v = f3 + (float)q23.y;
        // drive + blend
        h2v hd0 = H2(dv0.x), hd1 = H2(dv0.y);
        float xn0 = fmaf(oma, xo0, av * fmaxf(s0v + (float)hd0.x, 0.f));
        float xn1 = fmaf(oma, xo1, av * fmaxf(s1v + (float)hd0.y, 0.f));
        float xn2 = fmaf(oma, xo2, av * fmaxf(s2v + (float)hd1.x, 0.f));
        float xn3 = fmaf(oma, xo3, av * fmaxf(s3v + (float)hd1.y, 0.f));
        xo0 = xn0; xo1 = xn1; xo2 = xn2; xo3 = xn3;
        if (t >= s0 && h == 0) {
            *reinterpret_cast<float4*>(states_b + (size_t)(t + 1) * NH) =
                make_float4(xn0, xn1, xn2, xn3);
        }
        // each lane writes ONE pair dword (h selects even/odd pair)
        xsh[wslot] = h ? pkh(xn2, xn3) : pkh(xn0, xn1);
        // rotate ring
        dv0 = dv1; dv1 = dv2; dv2 = dv3; dv3 = dv4;
        dv4 = dv5; dv5 = dv6; dv6 = dv7; dv7 = dn;
    }
}

// ---------------------------------------------------------------------------
// Fallback scan (R12 verbatim, exact, non-chunked): if ws_size too small.
// ---------------------------------------------------------------------------
__global__ __attribute__((amdgpu_flat_work_group_size(64, 64),
                          amdgpu_waves_per_eu(1, 1)))
void rnn_scan_fb(
    const float* __restrict__ u, const float* __restrict__ p,
    const float* __restrict__ alpha, const float* __restrict__ noise,
    const float* __restrict__ W_rec, const float* __restrict__ W_in,
    float* __restrict__ states, int T)
{
    const int b    = blockIdx.x;
    const int lane = threadIdx.x;
    const int n0   = lane * 2;

    __shared__ unsigned int xsh[64];

    const float* wr0 = W_rec + (size_t)n0 * NH;
    const float* wr1 = wr0 + NH;
    LDW(0)  LDW(1)  LDW(2)  LDW(3)  LDW(4)  LDW(5)  LDW(6)  LDW(7)
    LDW(8)  LDW(9)  LDW(10) LDW(11) LDW(12) LDW(13) LDW(14) LDW(15)
    PIN_AB();

    const float wiA0 = W_in[n0 * NI + 0], wiA1 = W_in[n0 * NI + 1];
    const float wiA2 = W_in[n0 * NI + 2], wiA3 = W_in[n0 * NI + 3];
    const float wiA4 = W_in[n0 * NI + 4], wiA5 = W_in[n0 * NI + 5];
    const float wiB0 = W_in[(n0 + 1) * NI + 0], wiB1 = W_in[(n0 + 1) * NI + 1];
    const float wiB2 = W_in[(n0 + 1) * NI + 2], wiB3 = W_in[(n0 + 1) * NI + 3];
    const float wiB4 = W_in[(n0 + 1) * NI + 4], wiB5 = W_in[(n0 + 1) * NI + 5];

    const float2 pn   = *reinterpret_cast<const float2*>(p + (size_t)b * NH + n0);
    const float av    = alpha[0];
    const float oma   = 1.0f - av;
    const float scale = sqrtf(2.0f * av * SIGMA_REC * SIGMA_REC);

    const float* noise_b = noise + (size_t)b * T * NH + n0;
    unsigned int zv;
    asm volatile("v_mov_b32 %0, 0" : "=v"(zv));
    const float* u_b = u + (size_t)b * T * NI + zv;
    float* st_ptr = states + (size_t)b * T * NH + n0 + NH;

    xsh[lane] = 0u;
    *reinterpret_cast<float2*>(states + (size_t)b * T * NH + n0) = make_float2(0.f, 0.f);
    float xo0 = 0.0f, xo1 = 0.0f;

    auto LDnz = [&](int t) {
        return *reinterpret_cast<const float2*>(noise_b + (size_t)t * NH);
    };
    auto loadU = [&](int t) {
        const float2* up = reinterpret_cast<const float2*>(u_b + (size_t)t * NI);
        U6 r; r.a = up[0]; r.b = up[1]; r.c = up[2]; return r;
    };
    auto mkd = [&](float2 nz, const U6& uu) {
        float dx = fmaf(uu.a.x, wiA0, fmaf(uu.a.y, wiA1, fmaf(uu.b.x, wiA2,
                   fmaf(uu.b.y, wiA3, fmaf(uu.c.x, wiA4, fmaf(uu.c.y, wiA5,
                   fmaf(scale, nz.x, pn.x)))))));
        float dy = fmaf(uu.a.x, wiB0, fmaf(uu.a.y, wiB1, fmaf(uu.b.x, wiB2,
                   fmaf(uu.b.y, wiB3, fmaf(uu.c.x, wiB4, fmaf(uu.c.y, wiB5,
                   fmaf(scale, nz.y, pn.y)))))));
        return make_float2(dx, dy);
    };
    auto step = [&](float2 d) {
        const vu4* xr = reinterpret_cast<const vu4*>(xsh);
        float c00 = 0.f, c01 = 0.f, c02 = 0.f, c03 = 0.f;
        float c10 = 0.f, c11 = 0.f, c12 = 0.f, c13 = 0.f;
        vu4 xv0 = xr[0], xv1 = xr[1], xv2 = xr[2], xv3 = xr[3];
        vu4 xv4 = xr[4], xv5 = xr[5], xv6 = xr[6], xv7 = xr[7];
        DOT_OCT(0, xv0);  DOT_OCT(1, xv1);  DOT_OCT(2, xv2);  DOT_OCT(3, xv3);
        vu4 xv8 = xr[8], xv9 = xr[9], xv10 = xr[10], xv11 = xr[11];
        DOT_OCT(4, xv4);  DOT_OCT(5, xv5);  DOT_OCT(6, xv6);  DOT_OCT(7, xv7);
        vu4 xv12 = xr[12], xv13 = xr[13], xv14 = xr[14], xv15 = xr[15];
        DOT_OCT(8, xv8);  DOT_OCT(9, xv9);  DOT_OCT(10, xv10); DOT_OCT(11, xv11);
        DOT_OCT(12, xv12); DOT_OCT(13, xv13); DOT_OCT(14, xv14); DOT_OCT(15, xv15);
        float pre0 = ((c00 + c01) + (c02 + c03)) + d.x;
        float pre1 = ((c10 + c11) + (c12 + c13)) + d.y;
        float xn0 = fmaf(oma, xo0, av * fmaxf(pre0, 0.f));
        float xn1 = fmaf(oma, xo1, av * fmaxf(pre1, 0.f));
        xo0 = xn0; xo1 = xn1;
        *reinterpret_cast<float2*>(st_ptr) = make_float2(xn0, xn1);
        st_ptr += NH;
        xsh[lane] = pkh(xn0, xn1);
    };

    float2 nz0 = LDnz(0), nz1 = LDnz(1), nz2 = LDnz(2), nz3 = LDnz(3);
    U6 u0 = loadU(0), u1 = loadU(1), u2 = loadU(2), u3 = loadU(3);
    float2 nzA0 = LDnz(4), nzA1 = LDnz(5);   U6 uA0 = loadU(4), uA1 = loadU(5);
    float2 nzB0 = LDnz(6), nzB1 = LDnz(7);   U6 uB0 = loadU(6), uB1 = loadU(7);
    float2 d0 = mkd(nz0, u0), d1 = mkd(nz1, u1);
    float2 d2 = mkd(nz2, u2), d3 = mkd(nz3, u3);

    int t = 0;
    for (; t + 1 < T - 1; t += 2) {
        const int t8 = min(t + 8, T - 1), t9 = min(t + 9, T - 1);
        float2 nzC0 = LDnz(t8), nzC1 = LDnz(t9);
        U6 uC0 = loadU(t8), uC1 = loadU(t9);
        float2 dE = mkd(nzA0, uA0), dF = mkd(nzA1, uA1);
        step(d0);
        step(d1);
        d0 = d2; d1 = d3; d2 = dE; d3 = dF;
        nzA0 = nzB0; nzA1 = nzB1; uA0 = uB0; uA1 = uB1;
        nzB0 = nzC0; nzB1 = nzC1; uB0 = uC0; uB1 = uC1;
    }
    if (t < T - 1) step(d0);
}

// ---------------------------------------------------------------------------
// Projection: out[r,o] = sum_n relu(states[r,n]) * W_out[o,n]
// ---------------------------------------------------------------------------
__global__ __launch_bounds__(256) void out_proj_kernel(
    const float* __restrict__ states,  // [rows,128]
    const float* __restrict__ W_out,   // [2,128]
    float* __restrict__ out,           // [rows,2]
    int rows)
{
    const int wave = threadIdx.x >> 6;
    const int lane = threadIdx.x & 63;
    const int l    = lane & 31;
    const int row  = blockIdx.x * 8 + wave * 2 + (lane >> 5);
    if (row >= rows) return;

    float4 s = *reinterpret_cast<const float4*>(states + (size_t)row * NH + l * 4);
    s.x = fmaxf(s.x, 0.f); s.y = fmaxf(s.y, 0.f);
    s.z = fmaxf(s.z, 0.f); s.w = fmaxf(s.w, 0.f);
    float4 wa = reinterpret_cast<const float4*>(W_out)[l];
    float4 wb = reinterpret_cast<const float4*>(W_out + NH)[l];
    float c0 = s.x * wa.x + s.y * wa.y + s.z * wa.z + s.w * wa.w;
    float c1 = s.x * wb.x + s.y * wb.y + s.z * wb.z + s.w * wb.w;

#pragma unroll
    for (int off = 16; off >= 1; off >>= 1) {
        c0 += __shfl_xor(c0, off);
        c1 += __shfl_xor(c1, off);
    }
    if (l == 0) {
        *reinterpret_cast<float2*>(out + (size_t)row * 2) = make_float2(c0, c1);
    }
}

// ---------------------------------------------------------------------------
extern "C" void kernel_launch(void* const* d_in, const int* in_sizes, int n_in,
                              void* d_out, int out_size, void* d_ws, size_t ws_size,
                              hipStream_t stream) {
    const float* u     = (const float*)d_in[0];
    const float* p     = (const float*)d_in[1];
    const float* alpha = (const float*)d_in[2];
    const float* noise = (const float*)d_in[3];
    const float* W_rec = (const float*)d_in[4];
    const float* W_in  = (const float*)d_in[5];
    const float* W_out = (const float*)d_in[6];

    const int B = in_sizes[1] / NH;           // 128
    const int T = in_sizes[0] / (B * NI);     // 3000

    float* out    = (float*)d_out;                    // [B,T,2]
    float* states = out + (size_t)B * T * 2;          // [B,T,128]

    const size_t need = (size_t)B * T * 64 * sizeof(unsigned int);  // 98.3 MB
    if (d_ws != nullptr && ws_size >= need) {
        unsigned int* dpre = (unsigned int*)d_ws;
        drive_kernel<<<2048, 256, 0, stream>>>(u, p, alpha, noise, W_in,
                                               dpre, B, T);
        dim3 grid(B, NCHUNK);
        rnn_scan_pre<<<grid, 64, 0, stream>>>(W_rec, dpre, states, alpha, T);
    } else {
        rnn_scan_fb<<<B, 64, 0, stream>>>(u, p, alpha, noise, W_rec, W_in,
                                          states, T);
    }

    const int rows = B * T;
    out_proj_kernel<<<(rows + 7) / 8, 256, 0, stream>>>(states, W_out, out, rows);
}